// Round 7
// baseline (114.588 us; speedup 1.0000x reference)
//
#include <hip/hip_runtime.h>
#include <hip/hip_fp16.h>

// ---------------------------------------------------------------------------
// 9-qubit batched state-vector simulator, v7.
//  - fp16-packed LDS staging: (re,im) -> one 32-bit word via RNE pack
//    (NOT cvt_pkrtz: RTZ bias x8 round-trips ~ -0.8% on probs = too close to
//    threshold). Halves LDS traffic; b32 DS ops are conflict-free at 2/bank.
//  - gates / diagonals / init / epilogue remain fp32 packed (v_pk_*_f32 asm),
//    so fp16 rounding happens only 8x (round-trips), not per gate.
//  - one element per wave, 8 KB LDS/block, no __syncthreads.
//  - batch-independent tables (gate coeffs, boundary diagonals, init phase)
//    built by a one-block pre-kernel into d_ws.
// ---------------------------------------------------------------------------

typedef float v2f __attribute__((ext_vector_type(2)));

constexpr int pf(int l, int i) {        // forward CNOT-ring basis map, layer l
    const int r = l + 1; int j = i;
    for (int c = 0; c < 9; ++c) {
        const int bit = (j >> (8 - c)) & 1;
        const int t = (c + r) % 9;
        j ^= bit << (8 - t);
    }
    return j;
}
constexpr int sg(int i) { return i ^ (i >> 4); }   // LDS anti-conflict swizzle

struct PMask { int m[2][9]; };
constexpr PMask make_pmask() {
    PMask pm{};
    for (int bd = 0; bd < 2; ++bd)
        for (int q = 0; q < 9; ++q) {
            const int img = pf(bd, 1 << q);
            for (int p = 0; p < 9; ++p)
                if ((img >> p) & 1) pm.m[bd][p] |= 1 << q;
        }
    return pm;
}
constexpr PMask PM = make_pmask();

struct T3Tab { int laneBase[2][6]; int regPart[2][8]; };
constexpr T3Tab make_t3() {
    T3Tab t{};
    for (int l = 0; l < 2; ++l) {
        for (int b = 0; b < 6; ++b) t.laneBase[l][b] = sg(pf(l, 1 << b));
        for (int g = 0; g < 8; ++g) t.regPart [l][g] = sg(pf(l, g << 6));
    }
    return t;
}
constexpr T3Tab T3T = make_t3();

constexpr int sgk3(int k) { return (k << 3) ^ (k >> 1); }   // sg(k<<3)
constexpr int sgk6(int k) { return (k << 6) ^ (k << 2); }   // sg(k<<6)

#define PI_F    3.14159265358979323846f
#define INV2PI  0.15915494309189535f

// ws layout (floats):
//   [0..216)          gates: 27 x 8 floats {c,c,s,s,-s,-s,0,0}
//   [216..2264)       D0q: 512 float4 {dx,dx,-dy,dy}  boundary 1->2
//   [2264..4312)      D1q: 512 float4                 boundary 2->3
//   [4312..5336)      PH : 512 v2f init-state phase
__global__ __launch_bounds__(512) void qtab_kernel(
        const float* __restrict__ wt, float* __restrict__ ws) {
    const int j = threadIdx.x;             // 0..511
    if (j < 27) {
        float s, c; __sincosf(0.5f * wt[j * 3 + 1], &s, &c);
        float* g = ws + j * 8;
        g[0] = c;  g[1] = c;  g[2] = s;  g[3] = s;
        g[4] = -s; g[5] = -s; g[6] = 0.f; g[7] = 0.f;
    }
    float4* dq = (float4*)(ws + 216);
    #pragma unroll
    for (int bd = 0; bd < 2; ++bd) {
        float alpha = 0.0f;
        #pragma unroll
        for (int p = 0; p < 9; ++p) {
            const int w = 8 - p;
            const float om = wt[(bd * 9 + w) * 3 + 2];        // omega, layer bd
            const float ph = wt[((bd + 1) * 9 + w) * 3 + 0];  // phi, layer bd+1
            alpha += ((j >> p) & 1) ? 0.5f * om : -0.5f * om;
            alpha += (__popc(j & PM.m[bd][p]) & 1) ? 0.5f * ph : -0.5f * ph;
        }
        float sn, cs; __sincosf(alpha, &sn, &cs);
        dq[bd * 512 + j] = make_float4(cs, cs, -sn, sn);
    }
    {
        float a = 0.0f;
        #pragma unroll
        for (int p = 0; p < 9; ++p) {
            const int w = 8 - p;
            const float phi = wt[w * 3 + 0];
            a += ((j >> p) & 1) ? (0.5f * phi - 0.5f * PI_F) : (-0.5f * phi);
        }
        float sn, cs; __sincosf(a, &sn, &cs);
        ((v2f*)(ws + 4312))[j] = (v2f){cs, sn};
    }
}

// fp16 staging pack/unpack (RNE, unbiased)
static __device__ inline unsigned pack16(v2f a) {
    const __half2 h = __floats2half2_rn(a.x, a.y);
    return *(const unsigned*)&h;
}
static __device__ inline v2f unpack16(unsigned u) {
    const __half2 h = *(const __half2*)&u;
    const float2 f = __half22float2(h);
    return (v2f){f.x, f.y};
}

// packed real-Y gate: n0 = c*a0 - s*a1 ; n1 = s*a0 + c*a1  (re & im packed)
#define APPLY_GATE(gidx, KB)                                                  \
    {                                                                         \
        const float* gp = GT + (gidx) * 8;                                    \
        const v2f cc = *(const v2f*)(gp + 0);                                 \
        const v2f ss = *(const v2f*)(gp + 2);                                 \
        const v2f ns = *(const v2f*)(gp + 4);                                 \
        _Pragma("unroll")                                                     \
        for (int k0 = 0; k0 < 8; ++k0) if (!(k0 & (KB))) {                    \
            const int k1 = k0 | (KB);                                         \
            v2f t0, t1, n0, n1;                                               \
            asm("v_pk_mul_f32 %0, %1, %2" : "=v"(t0) : "v"(a[k1]), "s"(ns));  \
            asm("v_pk_mul_f32 %0, %1, %2" : "=v"(t1) : "v"(a[k1]), "s"(cc));  \
            asm("v_pk_fma_f32 %0, %1, %2, %3"                                 \
                : "=v"(n0) : "v"(a[k0]), "s"(cc), "v"(t0));                   \
            asm("v_pk_fma_f32 %0, %1, %2, %3"                                 \
                : "=v"(n1) : "v"(a[k0]), "s"(ss), "v"(t1));                   \
            a[k0] = n0; a[k1] = n1;                                           \
        }                                                                     \
    }

__global__ __launch_bounds__(256) void qsim_kernel(
        const float* __restrict__ x,       // (batch, 9)
        const float* __restrict__ tab,     // ws tables
        float* __restrict__ out,           // (batch, 9)
        int batch) {
    __shared__ unsigned st[4][512];        // per-wave fp16x2 staging (8 KiB)

    const int tid  = threadIdx.x;
    const int wv   = tid >> 6;
    const int lane = tid & 63;
    const int b    = blockIdx.x * 4 + wv;
    if (b >= batch) return;
    const int bu   = __builtin_amdgcn_readfirstlane(b);   // wave-uniform

    unsigned* __restrict__ S = st[wv];
    const float* __restrict__ GT = tab;
    const float4* __restrict__ D0 = (const float4*)(tab + 216);
    const float4* __restrict__ D1 = D0 + 512;
    const v2f*   __restrict__ PH = (const v2f*)(tab + 4312);

    // ---- init: magnitudes via HW trig (revolutions), phase from table ----
    float cx[9], sx[9];
    #pragma unroll
    for (int w = 0; w < 9; ++w) {
        const float rev = x[bu * 9 + w] * (0.5f * INV2PI);
        sx[w] = __builtin_amdgcn_sinf(rev);
        cx[w] = __builtin_amdgcn_cosf(rev);
    }
    float P = 1.0f;
    #pragma unroll
    for (int w = 0; w < 6; ++w)
        P *= ((lane >> (5 - w)) & 1) ? sx[w] : cx[w];

    v2f a[8];
    #pragma unroll
    for (int k = 0; k < 8; ++k) {
        const float m = P * ((k & 4) ? sx[6] : cx[6])
                          * ((k & 2) ? sx[7] : cx[7])
                          * ((k & 1) ? sx[8] : cx[8]);
        a[k] = PH[(lane << 3) | k] * m;
    }

    // ---- swizzled address bases ----
    const int baseA = (lane << 3) ^ (lane >> 1);            // sg(L<<3)
    const int hB    = ((lane & 0x38) << 3) | (lane & 7);
    const int baseB = hB ^ (hB >> 4);
    const int baseC = lane ^ (lane >> 4);
    int t3b[2];
    #pragma unroll
    for (int l = 0; l < 2; ++l) {
        int v = 0;
        #pragma unroll
        for (int bb = 0; bb < 6; ++bb)
            v ^= ((lane >> bb) & 1) ? T3T.laneBase[l][bb] : 0;
        t3b[l] = v;
    }

    // ---- 3 layers of 9 packed real-Ry gates, fp16 LDS layout cycling ----
    #pragma unroll
    for (int l = 0; l < 3; ++l) {
        APPLY_GATE(l * 9 + 6, 4);   // layout A: reg bits = qubits 6,7,8
        APPLY_GATE(l * 9 + 7, 2);
        APPLY_GATE(l * 9 + 8, 1);

        #pragma unroll
        for (int k = 0; k < 8; ++k) S[baseA ^ k] = pack16(a[k]);
        #pragma unroll
        for (int k = 0; k < 8; ++k) a[k] = unpack16(S[baseB ^ sgk3(k)]);

        APPLY_GATE(l * 9 + 3, 4);   // layout B: reg bits = qubits 3,4,5
        APPLY_GATE(l * 9 + 4, 2);
        APPLY_GATE(l * 9 + 5, 1);

        #pragma unroll
        for (int k = 0; k < 8; ++k) S[baseB ^ sgk3(k)] = pack16(a[k]);
        #pragma unroll
        for (int k = 0; k < 8; ++k) a[k] = unpack16(S[baseC ^ sgk6(k)]);

        APPLY_GATE(l * 9 + 0, 4);   // layout C: reg bits = qubits 0,1,2
        APPLY_GATE(l * 9 + 1, 2);
        APPLY_GATE(l * 9 + 2, 1);

        if (l < 2) {
            // packed boundary diagonal: a' = u*{dx,dx} + swap(u)*{-dy,dy}
            const float4* __restrict__ D = (l == 0) ? D0 : D1;
            #pragma unroll
            for (int k = 0; k < 8; ++k) {
                const float4 d = D[(k << 6) | lane];
                const v2f dd = (v2f){d.x, d.y};   // {dx,dx}
                const v2f dn = (v2f){d.z, d.w};   // {-dy,dy}
                v2f t, r;
                asm("v_pk_mul_f32 %0, %1, %2" : "=v"(t) : "v"(a[k]), "v"(dd));
                asm("v_pk_fma_f32 %0, %1, %2, %3 op_sel:[1,0,0] op_sel_hi:[0,1,1]"
                    : "=v"(r) : "v"(a[k]), "v"(dn), "v"(t));
                a[k] = r;
            }
            // T3: C -> A with the CNOT-ring permutation folded in
            #pragma unroll
            for (int k = 0; k < 8; ++k)
                S[t3b[l] ^ T3T.regPart[l][k]] = pack16(a[k]);
            #pragma unroll
            for (int k = 0; k < 8; ++k) a[k] = unpack16(S[baseA ^ k]);
        }
    }

    // ---- epilogue: fast Walsh-Hadamard over lanes ----
    float p[8];
    #pragma unroll
    for (int k = 0; k < 8; ++k) {
        const v2f q = a[k] * a[k];
        p[k] = q.x + q.y;
    }
    float F[4] = {0.f, 0.f, 0.f, 0.f};     // S, U4, U2, U1
    #pragma unroll
    for (int k = 0; k < 8; ++k) {
        F[0] += p[k];
        F[1] += (k & 4) ? -p[k] : p[k];
        F[2] += (k & 2) ? -p[k] : p[k];
        F[3] += (k & 1) ? -p[k] : p[k];
    }
    // 6-step FWHT butterfly: lane m ends with Sum_j (-1)^popc(j&m) F(j)
    #pragma unroll
    for (int d = 1; d < 64; d <<= 1) {
        const float sgn = (lane & d) ? -1.0f : 1.0f;
        #pragma unroll
        for (int w = 0; w < 4; ++w) {
            const float t = __shfl_xor(F[w], d, 64);
            F[w] = fmaf(sgn, F[w], t);
        }
    }
    // gather the 9 needed Walsh coefficients via LDS (reuse staging as float)
    float* Sf = (float*)S;
    Sf[2 * lane]           = F[0];
    Sf[2 * lane + 1]       = F[1];
    Sf[128 + 2 * lane]     = F[2];
    Sf[128 + 2 * lane + 1] = F[3];
    if (lane < 9) {
        const int idx = (lane == 0) ? 72  : (lane == 1) ? 36  : (lane == 2) ? 18
                      : (lane == 3) ? 65  : (lane == 4) ? 160 : (lane == 5) ? 145
                      : (lane == 6) ? 73  : (lane == 7) ? 164 : 147;
        out[bu * 9 + lane] = Sf[idx];
    }
}

extern "C" void kernel_launch(void* const* d_in, const int* in_sizes, int n_in,
                              void* d_out, int out_size, void* d_ws, size_t ws_size,
                              hipStream_t stream) {
    const float* x  = (const float*)d_in[0];   // (32768, 9) fp32
    const float* wt = (const float*)d_in[1];   // (3, 9, 3) fp32
    float* out = (float*)d_out;                // (32768, 9) fp32
    const int batch = in_sizes[0] / 9;
    float* ws = (float*)d_ws;                  // 5336 floats = 21.3 KB used

    hipLaunchKernelGGL(qtab_kernel, dim3(1), dim3(512), 0, stream, wt, ws);
    hipLaunchKernelGGL(qsim_kernel, dim3((batch + 3) / 4), dim3(256), 0, stream,
                       x, ws, out, batch);
}

// Round 8
// 109.622 us; speedup vs baseline: 1.0453x; 1.0453x over previous
//
#include <hip/hip_runtime.h>

// ---------------------------------------------------------------------------
// 9-qubit batched state-vector simulator, v8.
//  - v6 structure (fp32 b64 staging, XOR swizzle, 1 elem/wave, no barrier)
//  - KEY FIX: gate coefficients live in SGPRs. v6 reloaded {c,c},{s,s},{-s,-s}
//    from global per gate (81 scalar loads, SGPR=48 proves no hoist) ->
//    ~200cyc lgkmcnt stall inside every gate = ~5400 serial cycles/wave.
//    v8 stores ONE {c,s} SGPR pair per gate (54 SGPRs, loaded once) and
//    broadcasts c / s / -s per half via VOP3P op_sel/op_sel_hi/neg modifiers.
// ---------------------------------------------------------------------------

typedef float v2f __attribute__((ext_vector_type(2)));

constexpr int pf(int l, int i) {        // forward CNOT-ring basis map, layer l
    const int r = l + 1; int j = i;
    for (int c = 0; c < 9; ++c) {
        const int bit = (j >> (8 - c)) & 1;
        const int t = (c + r) % 9;
        j ^= bit << (8 - t);
    }
    return j;
}
constexpr int sg(int i) { return i ^ (i >> 4); }   // LDS anti-conflict swizzle

struct PMask { int m[2][9]; };
constexpr PMask make_pmask() {
    PMask pm{};
    for (int bd = 0; bd < 2; ++bd)
        for (int q = 0; q < 9; ++q) {
            const int img = pf(bd, 1 << q);
            for (int p = 0; p < 9; ++p)
                if ((img >> p) & 1) pm.m[bd][p] |= 1 << q;
        }
    return pm;
}
constexpr PMask PM = make_pmask();

struct T3Tab { int laneBase[2][6]; int regPart[2][8]; };
constexpr T3Tab make_t3() {
    T3Tab t{};
    for (int l = 0; l < 2; ++l) {
        for (int b = 0; b < 6; ++b) t.laneBase[l][b] = sg(pf(l, 1 << b));
        for (int g = 0; g < 8; ++g) t.regPart [l][g] = sg(pf(l, g << 6));
    }
    return t;
}
constexpr T3Tab T3T = make_t3();

constexpr int sgk3(int k) { return (k << 3) ^ (k >> 1); }   // sg(k<<3)
constexpr int sgk6(int k) { return (k << 6) ^ (k << 2); }   // sg(k<<6)

#define PI_F    3.14159265358979323846f
#define INV2PI  0.15915494309189535f

// ws layout (floats):
//   [0..54)           gates: 27 x {c, s}   (even-aligned pairs)
//   [64..2112)        D0q: 512 float4 {dx,dx,-dy,dy}  boundary 1->2
//   [2112..4160)      D1q: 512 float4                 boundary 2->3
//   [4160..5184)      PH : 512 v2f init-state phase
__global__ __launch_bounds__(512) void qtab_kernel(
        const float* __restrict__ wt, float* __restrict__ ws) {
    const int j = threadIdx.x;             // 0..511
    if (j < 27) {
        float s, c; __sincosf(0.5f * wt[j * 3 + 1], &s, &c);
        ws[2 * j]     = c;
        ws[2 * j + 1] = s;
    }
    float4* dq = (float4*)(ws + 64);
    #pragma unroll
    for (int bd = 0; bd < 2; ++bd) {
        float alpha = 0.0f;
        #pragma unroll
        for (int p = 0; p < 9; ++p) {
            const int w = 8 - p;
            const float om = wt[(bd * 9 + w) * 3 + 2];        // omega, layer bd
            const float ph = wt[((bd + 1) * 9 + w) * 3 + 0];  // phi, layer bd+1
            alpha += ((j >> p) & 1) ? 0.5f * om : -0.5f * om;
            alpha += (__popc(j & PM.m[bd][p]) & 1) ? 0.5f * ph : -0.5f * ph;
        }
        float sn, cs; __sincosf(alpha, &sn, &cs);
        dq[bd * 512 + j] = make_float4(cs, cs, -sn, sn);
    }
    {
        float a = 0.0f;
        #pragma unroll
        for (int p = 0; p < 9; ++p) {
            const int w = 8 - p;
            const float phi = wt[w * 3 + 0];
            a += ((j >> p) & 1) ? (0.5f * phi - 0.5f * PI_F) : (-0.5f * phi);
        }
        float sn, cs; __sincosf(a, &sn, &cs);
        ((v2f*)(ws + 4160))[j] = (v2f){cs, sn};
    }
}

// packed real-Y gate, coefficients broadcast from ONE SGPR pair G={c,s}:
//   n0 = c*a0 - s*a1 ; n1 = s*a0 + c*a1   (re & im packed in each v2f)
// op_sel/op_sel_hi pick the c (low) or s (high) word for both halves;
// neg_lo/neg_hi give -s. Vector sources use default word selection.
#define APPLY_GATE(gidx, KB)                                                  \
    {                                                                         \
        const v2f G = gg[(gidx)];                                             \
        _Pragma("unroll")                                                     \
        for (int k0 = 0; k0 < 8; ++k0) if (!(k0 & (KB))) {                    \
            const int k1 = k0 | (KB);                                         \
            v2f t0, t1, n0, n1;                                               \
            asm("v_pk_mul_f32 %0, %1, %2 op_sel:[0,1] op_sel_hi:[1,1] "       \
                "neg_lo:[0,1] neg_hi:[0,1]"                                   \
                : "=v"(t0) : "v"(a[k1]), "s"(G));        /* -s * a1 */        \
            asm("v_pk_mul_f32 %0, %1, %2 op_sel:[0,0] op_sel_hi:[1,0]"        \
                : "=v"(t1) : "v"(a[k1]), "s"(G));        /*  c * a1 */        \
            asm("v_pk_fma_f32 %0, %1, %2, %3 op_sel:[0,0,0] op_sel_hi:[1,0,1]"\
                : "=v"(n0) : "v"(a[k0]), "s"(G), "v"(t0)); /* c*a0 - s*a1 */  \
            asm("v_pk_fma_f32 %0, %1, %2, %3 op_sel:[0,1,0] op_sel_hi:[1,1,1]"\
                : "=v"(n1) : "v"(a[k0]), "s"(G), "v"(t1)); /* s*a0 + c*a1 */  \
            a[k0] = n0; a[k1] = n1;                                           \
        }                                                                     \
    }

__global__ __launch_bounds__(256) void qsim_kernel(
        const float* __restrict__ x,       // (batch, 9)
        const float* __restrict__ tab,     // ws tables
        float* __restrict__ out,           // (batch, 9)
        int batch) {
    __shared__ v2f st[4][512];             // per-wave staging (16 KiB)

    const int tid  = threadIdx.x;
    const int wv   = tid >> 6;
    const int lane = tid & 63;
    const int b    = blockIdx.x * 4 + wv;
    if (b >= batch) return;
    const int bu   = __builtin_amdgcn_readfirstlane(b);   // wave-uniform

    v2f* __restrict__ S = st[wv];
    const float4* __restrict__ D0 = (const float4*)(tab + 64);
    const float4* __restrict__ D1 = D0 + 512;
    const v2f*   __restrict__ PH = (const v2f*)(tab + 4160);

    // ---- hoist ALL 27 gate {c,s} pairs into SGPRs (one wait, reused) ----
    v2f gg[27];
    #pragma unroll
    for (int g = 0; g < 27; ++g)
        gg[g] = ((const v2f*)tab)[g];

    // ---- init: magnitudes via HW trig (revolutions), phase from table ----
    float cx[9], sx[9];
    #pragma unroll
    for (int w = 0; w < 9; ++w) {
        const float rev = x[bu * 9 + w] * (0.5f * INV2PI);
        sx[w] = __builtin_amdgcn_sinf(rev);
        cx[w] = __builtin_amdgcn_cosf(rev);
    }
    float P = 1.0f;
    #pragma unroll
    for (int w = 0; w < 6; ++w)
        P *= ((lane >> (5 - w)) & 1) ? sx[w] : cx[w];

    v2f a[8];
    #pragma unroll
    for (int k = 0; k < 8; ++k) {
        const float m = P * ((k & 4) ? sx[6] : cx[6])
                          * ((k & 2) ? sx[7] : cx[7])
                          * ((k & 1) ? sx[8] : cx[8]);
        a[k] = PH[(lane << 3) | k] * m;
    }

    // ---- swizzled address bases ----
    const int baseA = (lane << 3) ^ (lane >> 1);            // sg(L<<3)
    const int hB    = ((lane & 0x38) << 3) | (lane & 7);
    const int baseB = hB ^ (hB >> 4);
    const int baseC = lane ^ (lane >> 4);
    int t3b[2];
    #pragma unroll
    for (int l = 0; l < 2; ++l) {
        int v = 0;
        #pragma unroll
        for (int bb = 0; bb < 6; ++bb)
            v ^= ((lane >> bb) & 1) ? T3T.laneBase[l][bb] : 0;
        t3b[l] = v;
    }

    // ---- 3 layers of 9 packed real-Ry gates, swizzled LDS layout cycling ----
    #pragma unroll
    for (int l = 0; l < 3; ++l) {
        APPLY_GATE(l * 9 + 6, 4);   // layout A: reg bits = qubits 6,7,8
        APPLY_GATE(l * 9 + 7, 2);
        APPLY_GATE(l * 9 + 8, 1);

        #pragma unroll
        for (int k = 0; k < 8; ++k) S[baseA ^ k] = a[k];
        #pragma unroll
        for (int k = 0; k < 8; ++k) a[k] = S[baseB ^ sgk3(k)];

        APPLY_GATE(l * 9 + 3, 4);   // layout B: reg bits = qubits 3,4,5
        APPLY_GATE(l * 9 + 4, 2);
        APPLY_GATE(l * 9 + 5, 1);

        #pragma unroll
        for (int k = 0; k < 8; ++k) S[baseB ^ sgk3(k)] = a[k];
        #pragma unroll
        for (int k = 0; k < 8; ++k) a[k] = S[baseC ^ sgk6(k)];

        APPLY_GATE(l * 9 + 0, 4);   // layout C: reg bits = qubits 0,1,2
        APPLY_GATE(l * 9 + 1, 2);
        APPLY_GATE(l * 9 + 2, 1);

        if (l < 2) {
            // packed boundary diagonal: a' = u*{dx,dx} + swap(u)*{-dy,dy}
            const float4* __restrict__ D = (l == 0) ? D0 : D1;
            #pragma unroll
            for (int k = 0; k < 8; ++k) {
                const float4 d = D[(k << 6) | lane];
                const v2f dd = (v2f){d.x, d.y};   // {dx,dx}
                const v2f dn = (v2f){d.z, d.w};   // {-dy,dy}
                v2f t, r;
                asm("v_pk_mul_f32 %0, %1, %2" : "=v"(t) : "v"(a[k]), "v"(dd));
                asm("v_pk_fma_f32 %0, %1, %2, %3 op_sel:[1,0,0] op_sel_hi:[0,1,1]"
                    : "=v"(r) : "v"(a[k]), "v"(dn), "v"(t));
                a[k] = r;
            }
            // T3: C -> A with the CNOT-ring permutation folded in
            #pragma unroll
            for (int k = 0; k < 8; ++k)
                S[t3b[l] ^ T3T.regPart[l][k]] = a[k];
            #pragma unroll
            for (int k = 0; k < 8; ++k) a[k] = S[baseA ^ k];
        }
    }

    // ---- epilogue: fast Walsh-Hadamard over lanes ----
    float p[8];
    #pragma unroll
    for (int k = 0; k < 8; ++k) {
        const v2f q = a[k] * a[k];
        p[k] = q.x + q.y;
    }
    float F[4] = {0.f, 0.f, 0.f, 0.f};     // S, U4, U2, U1
    #pragma unroll
    for (int k = 0; k < 8; ++k) {
        F[0] += p[k];
        F[1] += (k & 4) ? -p[k] : p[k];
        F[2] += (k & 2) ? -p[k] : p[k];
        F[3] += (k & 1) ? -p[k] : p[k];
    }
    // 6-step FWHT butterfly: lane m ends with Sum_j (-1)^popc(j&m) F(j)
    #pragma unroll
    for (int d = 1; d < 64; d <<= 1) {
        const float sgn = (lane & d) ? -1.0f : 1.0f;
        #pragma unroll
        for (int w = 0; w < 4; ++w) {
            const float t = __shfl_xor(F[w], d, 64);
            F[w] = fmaf(sgn, F[w], t);
        }
    }
    // gather the 9 needed Walsh coefficients via LDS (reuse staging as float)
    float* Sf = (float*)S;
    Sf[2 * lane]           = F[0];
    Sf[2 * lane + 1]       = F[1];
    Sf[128 + 2 * lane]     = F[2];
    Sf[128 + 2 * lane + 1] = F[3];
    if (lane < 9) {
        const int idx = (lane == 0) ? 72  : (lane == 1) ? 36  : (lane == 2) ? 18
                      : (lane == 3) ? 65  : (lane == 4) ? 160 : (lane == 5) ? 145
                      : (lane == 6) ? 73  : (lane == 7) ? 164 : 147;
        out[bu * 9 + lane] = Sf[idx];
    }
}

extern "C" void kernel_launch(void* const* d_in, const int* in_sizes, int n_in,
                              void* d_out, int out_size, void* d_ws, size_t ws_size,
                              hipStream_t stream) {
    const float* x  = (const float*)d_in[0];   // (32768, 9) fp32
    const float* wt = (const float*)d_in[1];   // (3, 9, 3) fp32
    float* out = (float*)d_out;                // (32768, 9) fp32
    const int batch = in_sizes[0] / 9;
    float* ws = (float*)d_ws;                  // 5184 floats = 20.7 KB used

    hipLaunchKernelGGL(qtab_kernel, dim3(1), dim3(512), 0, stream, wt, ws);
    hipLaunchKernelGGL(qsim_kernel, dim3((batch + 3) / 4), dim3(256), 0, stream,
                       x, ws, out, batch);
}